// Round 4
// baseline (513.519 us; speedup 1.0000x reference)
//
#include <hip/hip_runtime.h>
#include <stdint.h>

#define N_ROWS 131072
#define D_IN   512
#define D_OUT  512
#define BM     64
#define THREADS 512
#define LDA    520                    // padded bf16 row stride: 1040 B = 260 dwords ≡ 4 (mod 32)
#define LDS_BYTES (BM * LDA * 2)      // 66560 B -> 2 blocks/CU

typedef short  s8v __attribute__((ext_vector_type(8)));   // 8 bf16 bits (4 VGPRs)
typedef float  f4v __attribute__((ext_vector_type(4)));   // MFMA acc
typedef unsigned int u32;

// fp32 -> bf16 bits, round-to-nearest-even (exact for 0.0/1.0 spike inputs)
__device__ __forceinline__ unsigned short f2bf(float f) {
    u32 b = __builtin_bit_cast(u32, f);
    b += 0x7FFFu + ((b >> 16) & 1u);
    return (unsigned short)(b >> 16);
}

// ---------------------------------------------------------------------------
// W fp32 [k][n] -> Wb bf16, k-tiled transpose: Wb[(kt*512 + n)*32 + kk] =
// bf16(W[(kt*32 + kk)*512 + n]).  In this layout a GEMM B-fragment read
// (n = base+c varies over 16 lanes, kk = q*8..q*8+7) is 64 lanes x 16 B
// FULLY CONTIGUOUS = one perfectly-coalesced 1 KB L2 transaction.
// ---------------------------------------------------------------------------
__global__ void convert_w(const float* __restrict__ W, unsigned short* __restrict__ wb) {
    int t  = blockIdx.x * blockDim.x + threadIdx.x;   // 0 .. 262143
    int kk = t & 31;
    int n  = (t >> 5) & 511;
    int kt = t >> 14;
    wb[t] = f2bf(W[(kt * 32 + kk) * 512 + n]);
}

// ---------------------------------------------------------------------------
// y = x @ W + b.  BM=64 rows/block, BN=512 (full D_OUT -> X read exactly once).
// A: whole 64x512 tile staged ONCE in LDS as bf16 (stride 520: frag reads are
//    bank-uniform 8 dwords/bank = wave64-b128 minimum).  ONE barrier total.
// B: NO LDS staging -- direct 1KB-coalesced b128 loads from the L2-resident
//    512 KB k-tiled Wb, depth-2 register ping-pong prefetch.
// The per-k-tile barrier+vmcnt(0) phase cost (~6.5K cyc/phase, measured
// constant across R0/R2) is eliminated entirely.
// ---------------------------------------------------------------------------
__global__ __launch_bounds__(THREADS, 4) void sparse_dense_gemm(
    const float* __restrict__ X, const unsigned short* __restrict__ Wb,
    const float* __restrict__ bias, float* __restrict__ Y)
{
    extern __shared__ char smem[];
    unsigned short* Ash = (unsigned short*)smem;     // [64][520] bf16

    const int tid  = threadIdx.x;
    const int lane = tid & 63;
    const int wv   = tid >> 6;          // 0..7
    const int r0   = blockIdx.x * BM;
    const int c    = lane & 15;         // frag row/col selector
    const int q    = lane >> 4;         // quad 0..3 -> k-slot q*8..q*8+7

    // ---- stage A: X[r0..r0+64) x 512 fp32 (contiguous 128 KB) -> bf16 LDS ----
    // 16 float4 loads issued back-to-back: 256 B/thread = 128 KB/block of HBM MLP.
    const float4* Xblk = (const float4*)(X + (size_t)r0 * D_IN);
    {
        const int row0 = tid >> 7;           // 0..3
        const int col  = (tid & 127) * 4;    // 0..508
        float4 v[16];
        #pragma unroll
        for (int i = 0; i < 16; ++i) v[i] = Xblk[i * 512 + tid];
        #pragma unroll
        for (int i = 0; i < 16; ++i) {
            u32 lo = (u32)f2bf(v[i].x) | ((u32)f2bf(v[i].y) << 16);
            u32 hi = (u32)f2bf(v[i].z) | ((u32)f2bf(v[i].w) << 16);
            *(uint2*)(Ash + (i * 4 + row0) * LDA + col) = make_uint2(lo, hi);
        }
    }

    // ---- per-lane B base: slab it at Wb + it*16384; frag(nf) at + nf*512 ----
    const unsigned short* Bp = Wb + (wv * 64 + c) * 32 + q * 8;

    f4v acc[4][4];
    #pragma unroll
    for (int mf = 0; mf < 4; ++mf)
        #pragma unroll
        for (int nf = 0; nf < 4; ++nf)
            acc[mf][nf] = f4v{0.f, 0.f, 0.f, 0.f};

    // prologue: steps 0 and 1 in flight before the barrier
    s8v b0[4], b1[4];
    #pragma unroll
    for (int nf = 0; nf < 4; ++nf) b0[nf] = *(const s8v*)(Bp + 0 * 16384 + nf * 512);
    #pragma unroll
    for (int nf = 0; nf < 4; ++nf) b1[nf] = *(const s8v*)(Bp + 1 * 16384 + nf * 512);

    __syncthreads();                    // the ONLY barrier

    const unsigned short* Arow = Ash + c * LDA + q * 8;

    // 16 k-steps, depth-2 ping-pong B prefetch, barrier-free
    #pragma unroll
    for (int it2 = 0; it2 < 8; ++it2) {
        const int itE = 2 * it2, itO = itE + 1;
        #pragma unroll
        for (int mf = 0; mf < 4; ++mf) {
            s8v af = *(const s8v*)(Arow + (mf * 16) * LDA + itE * 32);
            #pragma unroll
            for (int nf = 0; nf < 4; ++nf)
                acc[mf][nf] = __builtin_amdgcn_mfma_f32_16x16x32_bf16(
                    af, b0[nf], acc[mf][nf], 0, 0, 0);
        }
        if (itE + 2 < 16) {
            #pragma unroll
            for (int nf = 0; nf < 4; ++nf)
                b0[nf] = *(const s8v*)(Bp + (itE + 2) * 16384 + nf * 512);
        }
        #pragma unroll
        for (int mf = 0; mf < 4; ++mf) {
            s8v af = *(const s8v*)(Arow + (mf * 16) * LDA + itO * 32);
            #pragma unroll
            for (int nf = 0; nf < 4; ++nf)
                acc[mf][nf] = __builtin_amdgcn_mfma_f32_16x16x32_bf16(
                    af, b1[nf], acc[mf][nf], 0, 0, 0);
        }
        if (itO + 2 < 16) {
            #pragma unroll
            for (int nf = 0; nf < 4; ++nf)
                b1[nf] = *(const s8v*)(Bp + (itO + 2) * 16384 + nf * 512);
        }
    }

    // ---- epilogue: C/D layout col=lane&15, row=(lane>>4)*4+i (verified mapping) ----
    #pragma unroll
    for (int nf = 0; nf < 4; ++nf) {
        int col = wv * 64 + nf * 16 + c;
        float bv = bias[col];
        #pragma unroll
        for (int mf = 0; mf < 4; ++mf) {
            #pragma unroll
            for (int i = 0; i < 4; ++i) {
                int row = r0 + mf * 16 + q * 4 + i;
                Y[(size_t)row * D_OUT + col] = acc[mf][nf][i] + bv;
            }
        }
    }
}

extern "C" void kernel_launch(void* const* d_in, const int* in_sizes, int n_in,
                              void* d_out, int out_size, void* d_ws, size_t ws_size,
                              hipStream_t stream) {
    const float* X    = (const float*)d_in[0];
    const float* W    = (const float*)d_in[1];
    const float* bias = (const float*)d_in[2];
    float* Y          = (float*)d_out;
    unsigned short* wsb = (unsigned short*)d_ws;   // 512 KB bf16 k-tiled W^T copy

    (void)hipFuncSetAttribute((const void*)sparse_dense_gemm,
                              hipFuncAttributeMaxDynamicSharedMemorySize, LDS_BYTES);

    convert_w<<<1024, 256, 0, stream>>>(W, wsb);
    sparse_dense_gemm<<<N_ROWS / BM, THREADS, LDS_BYTES, stream>>>(X, wsb, bias, Y);
}